// Round 4
// baseline (134.949 us; speedup 1.0000x reference)
//
#include <hip/hip_runtime.h>

#define K_DIM 131072
#define NROW 256
#define BK 16
#define TPB 1024
#define TEMP 14.285714285714286f

typedef float f32x4  __attribute__((ext_vector_type(4)));
typedef float f32x16 __attribute__((ext_vector_type(16)));
typedef short s16x8  __attribute__((ext_vector_type(8)));
typedef unsigned int u32;

typedef const __attribute__((address_space(1))) void gvoid;
typedef __attribute__((address_space(3))) void lvoid;

__device__ __forceinline__ u32 cvt_pk_bf16(float lo, float hi) {
    u32 r;
    asm("v_cvt_pk_bf16_f32 %0, %1, %2" : "=v"(r) : "v"(lo), "v"(hi));
    return r;
}

// Read one bf16 MFMA fragment (8 consecutive k f32) from a swizzled fp32 LDS
// tile with 64-B rows. kh = lane>>5 selects k-half. chunk ^= row&3 both sides.
__device__ __forceinline__ s16x8 rd_frag(const float* base, int row, int kh) {
    const char* p = (const char*)base + row * 64;
    const int sw = row & 3;
    f32x4 lo = *(const f32x4*)(p + ((kh * 2)     ^ sw) * 16);
    f32x4 hi = *(const f32x4*)(p + ((kh * 2 + 1) ^ sw) * 16);
    union { u32 u[4]; s16x8 s; } r;
    r.u[0] = cvt_pk_bf16(lo.x, lo.y);
    r.u[1] = cvt_pk_bf16(lo.z, lo.w);
    r.u[2] = cvt_pk_bf16(hi.x, hi.y);
    r.u[3] = cvt_pk_bf16(hi.z, hi.w);
    return r.s;
}

// Stage 1: split-K GEMM, A-row-half C (128x256) per block. Pairs (g, g+8)
// share a k-chunk and an XCD (g%8), so the pair's duplicate B reads hit L2.
// 48 KB LDS + VGPR<=64 -> 2 independent blocks/CU (two barrier domains hide
// each other's load-tail stalls). gload_lds fp32, counted vmcnt, cvt-on-read.
__global__ __launch_bounds__(TPB, 8) void gemm_half(
    const float* __restrict__ A, const float* __restrict__ Bm,
    float* __restrict__ partials, int KC)
{
    __shared__ __align__(16) float As[2][128 * BK];  // 8 KB per buf
    __shared__ __align__(16) float Bs[2][256 * BK];  // 16 KB per buf

    const int g = blockIdx.x;
    const int k = ((g >> 4) << 3) | (g & 7);  // k-chunk id
    const int h = (g >> 3) & 1;               // A row-half

    const int t    = threadIdx.x;
    const int lane = t & 63;
    const int w    = t >> 6;          // 0..15
    const int wm   = (w >> 2) * 32;   // wave row base within half
    const int wn   = (w & 3) * 64;    // wave col base

    const long k0 = (long)k * KC;
    const int  NS = KC / BK;

    // staging: seg = 16 rows x 64 B; lane -> row = lane>>2, chunk = lane&3.
    // LDS dest linear (HW: base + lane*16); source chunk pre-swizzled ^row&3.
    const int  srow   = lane >> 2;
    const int  schunk = (lane & 3) ^ (srow & 3);
    const long soff   = (long)srow * K_DIM + (long)schunk * 4;

    // wave w<8: stages A seg w AND B seg w; wave w>=8: stages B seg w only.
    const float* aSrc = A  + (long)(h * 128 + w * 16) * K_DIM + k0 + soff;
    const float* bSrc = Bm + (long)(w * 16)           * K_DIM + k0 + soff;
    const bool   hasA = (w < 8);

#define ISSUE(TILE, BUF)                                                      \
    do {                                                                      \
        const long o_ = (long)(TILE) * BK;                                    \
        if (hasA)                                                             \
            __builtin_amdgcn_global_load_lds((gvoid*)(aSrc + o_),             \
                (lvoid*)&As[BUF][w * 256], 16, 0, 0);                         \
        __builtin_amdgcn_global_load_lds((gvoid*)(bSrc + o_),                 \
            (lvoid*)&Bs[BUF][w * 256], 16, 0, 0);                            \
    } while (0)

    // wait until tile-i loads done (tile i+1 stays in flight), then barrier
#define WAIT_TILE_BARRIER                                                     \
    do {                                                                      \
        if (hasA) asm volatile("s_waitcnt vmcnt(2)" ::: "memory");            \
        else      asm volatile("s_waitcnt vmcnt(1)" ::: "memory");            \
        __builtin_amdgcn_s_barrier();                                         \
    } while (0)

    const int rowA  = wm + (lane & 31);
    const int rowB0 = wn + (lane & 31);
    const int rowB1 = rowB0 + 32;
    const int kh    = lane >> 5;

    f32x16 acc0 = {0.f}, acc1 = {0.f};

#define COMPUTE(BUF)                                                          \
    do {                                                                      \
        const float* as_ = As[BUF];                                           \
        const float* bs_ = Bs[BUF];                                           \
        s16x8 af = rd_frag(as_, rowA,  kh);                                   \
        s16x8 b0 = rd_frag(bs_, rowB0, kh);                                   \
        s16x8 b1 = rd_frag(bs_, rowB1, kh);                                   \
        acc0 = __builtin_amdgcn_mfma_f32_32x32x16_bf16(af, b0, acc0, 0, 0, 0);\
        acc1 = __builtin_amdgcn_mfma_f32_32x32x16_bf16(af, b1, acc1, 0, 0, 0);\
    } while (0)

    // prologue: tiles 0 and 1 in flight
    ISSUE(0, 0);
    ISSUE(1, 1);

    for (int i = 0; i + 2 < NS; ++i) {
        WAIT_TILE_BARRIER;
        COMPUTE(i & 1);
        // all waves done reading buf before it is overwritten
        asm volatile("s_waitcnt lgkmcnt(0)" ::: "memory");
        __builtin_amdgcn_s_barrier();
        ISSUE(i + 2, i & 1);
    }
    WAIT_TILE_BARRIER;
    COMPUTE((NS - 2) & 1);
    asm volatile("s_waitcnt vmcnt(0)" ::: "memory");
    __builtin_amdgcn_s_barrier();
    COMPUTE((NS - 1) & 1);

#undef ISSUE
#undef WAIT_TILE_BARRIER
#undef COMPUTE

    // epilogue: C/D map col=lane&31, row=(reg&3)+8*(reg>>2)+4*(lane>>5)
    float* outp = partials + (size_t)k * (NROW * NROW);
    const int ccol = wn + (lane & 31);
    const int rb   = h * 128 + wm + (lane >> 5) * 4;
#pragma unroll
    for (int r = 0; r < 16; ++r) {
        const int crow = rb + (r & 3) + 8 * (r >> 2);
        outp[(size_t)crow * NROW + ccol]      = acc0[r];
        outp[(size_t)crow * NROW + ccol + 32] = acc1[r];
    }
}

// Stage 2: reduce partials over split; per-row masked exp, rowsum, pos, rowloss; store E.
__global__ __launch_bounds__(NROW) void reduce_loss_rows(
    const float* __restrict__ partials, const int* __restrict__ idx,
    float* __restrict__ E, float* __restrict__ rowloss, float* __restrict__ posbuf,
    int split)
{
    const int b = blockIdx.x;   // row
    const int t = threadIdx.x;  // col
    const float* p = partials + b * NROW + t;
    float sum = 0.f;
#pragma unroll 8
    for (int s = 0; s < split; ++s)
        sum += p[(size_t)s * (NROW * NROW)];

    const float logit = sum * TEMP;
    const bool  mask  = (idx[b] != idx[t]) || (b == t);
    const float e     = mask ? expf(logit) : 0.0f;
    E[b * NROW + t] = e;

    __shared__ float red[NROW];
    __shared__ float posv;
    if (t == b) posv = logit;
    red[t] = e;
    __syncthreads();
#pragma unroll
    for (int s = NROW / 2; s > 0; s >>= 1) {
        if (t < s) red[t] += red[t + s];
        __syncthreads();
    }
    if (t == 0) {
        posbuf[b]  = posv;
        rowloss[b] = logf(red[0]) - posv;
    }
}

// Stage 3: column sums of E, column losses, final mean.
__global__ __launch_bounds__(NROW) void finalize_loss(
    const float* __restrict__ E, const float* __restrict__ rowloss,
    const float* __restrict__ posbuf, float* __restrict__ out)
{
    const int t = threadIdx.x;
    float csum = 0.f;
#pragma unroll 8
    for (int i = 0; i < NROW; ++i)
        csum += E[i * NROW + t];
    const float closs = logf(csum) - posbuf[t];
    const float rl    = rowloss[t];

    __shared__ float redc[NROW];
    __shared__ float redr[NROW];
    redc[t] = closs;
    redr[t] = rl;
    __syncthreads();
#pragma unroll
    for (int s = NROW / 2; s > 0; s >>= 1) {
        if (t < s) { redc[t] += redc[t + s]; redr[t] += redr[t + s]; }
        __syncthreads();
    }
    if (t == 0)
        out[0] = 0.5f * (redc[0] + redr[0]) * (1.0f / (float)NROW);
}

extern "C" void kernel_launch(void* const* d_in, const int* in_sizes, int n_in,
                              void* d_out, int out_size, void* d_ws, size_t ws_size,
                              hipStream_t stream)
{
    (void)in_sizes; (void)n_in; (void)out_size;
    const float* A   = (const float*)d_in[0];
    const float* Bm  = (const float*)d_in[1];
    const int*   idx = (const int*)d_in[2];
    float*       out = (float*)d_out;

    // adaptive split-K based on workspace size (partials: split * 256KB)
    int split = 256;
    const size_t extra = (size_t)(NROW * NROW + 2 * NROW) * sizeof(float);
    while (split > 8 &&
           (size_t)split * NROW * NROW * sizeof(float) + extra > ws_size)
        split >>= 1;
    const int KC = K_DIM / split;

    float* partials = (float*)d_ws;
    float* E        = partials + (size_t)split * NROW * NROW;
    float* rowloss  = E + NROW * NROW;
    float* posbuf   = rowloss + NROW;

    gemm_half<<<split * 2, TPB, 0, stream>>>(A, Bm, partials, KC);
    reduce_loss_rows<<<NROW, NROW, 0, stream>>>(partials, idx, E, rowloss, posbuf, split);
    finalize_loss<<<1, NROW, 0, stream>>>(E, rowloss, posbuf, out);
}

// Round 5
// 108.615 us; speedup vs baseline: 1.2425x; 1.2425x over previous
//
#include <hip/hip_runtime.h>

#define K_DIM 131072
#define NROW 256
#define KC 512
#define BK 32
#define NS 16
#define SPLIT 256
#define TPB 1024
#define TEMP 14.285714285714286f

typedef float f32x4 __attribute__((ext_vector_type(4)));
typedef short s16x8 __attribute__((ext_vector_type(8)));
typedef unsigned int u32;
typedef u32 u32x4 __attribute__((ext_vector_type(4)));

typedef const __attribute__((address_space(1))) void gvoid;
typedef __attribute__((address_space(3))) void lvoid;

__device__ __forceinline__ u32 cvt_pk_bf16(float lo, float hi) {
    u32 r;
    asm("v_cvt_pk_bf16_f32 %0, %1, %2" : "=v"(r) : "v"(lo), "v"(hi));
    return r;
}

// Stage 1: split-K GEMM. Block pair (g, g+256) shares k-chunk k=g&255; h=g>>8
// picks the A-row half. Same (g%8) -> same XCD, co-resident at 2 blocks/CU ->
// sibling's duplicate B read hits L2/L3 within a tile-time.
// 16 waves as 8x2: wave strip = 16 rows x 128 cols -> acc = 8 x f32x4 = 32 VGPR.
// A: fp32 LDS via global_load_lds (linear dest, involution source-swizzle).
// B: register-staged, cvt to bf16, LDS rows padded to 80 B (bank-spread, b128-aligned).
__global__ __launch_bounds__(TPB, 8) void gemm_pair(
    const float* __restrict__ A, const float* __restrict__ Bm,
    float* __restrict__ partials)
{
    __shared__ __align__(16) float As[2][128 * BK];            // 16 KB per buf
    __shared__ __align__(16) unsigned short Bs[2][256 * 40];   // 20 KB per buf

    const int g = blockIdx.x;
    const int k = g & 255;
    const int h = g >> 8;

    const int t    = threadIdx.x;
    const int lane = t & 63;
    const int w    = t >> 6;          // 0..15
    const int wr   = (w >> 1) * 16;   // wave row base within 128-half
    const int wc   = (w & 1) * 128;   // wave col base

    // ---- A staging: wave w stages rows [8w, 8w+8) of the half; 1 gload/tile.
    // LDS dest linear (HW: uniform base + lane*16); source chunk = (l&7)^(l>>3)
    // so LDS[row][c] holds global chunk c^(row&7) (involution).
    const int adrow = lane >> 3;            // 0..7
    const int asch  = (lane & 7) ^ adrow;   // swizzled source 16B-chunk
    const float* aSrc = A + (long)(h * 128 + w * 8 + adrow) * K_DIM
                          + (long)k * KC + asch * 4;

    // ---- B staging (regs): thread t -> row t>>2, f32 cols (t&3)*8 .. +8
    const int brow = t >> 2;
    const float* bSrc = Bm + (long)brow * K_DIM + (long)k * KC + (t & 3) * 8;
    char* const bDst0 = (char*)&Bs[0][0] + brow * 80 + (t & 3) * 16;
    char* const bDst1 = (char*)&Bs[1][0] + brow * 80 + (t & 3) * 16;

    // ---- fragment-read constants
    const int arow  = wr + (lane & 15);
    const int aoff0 = arow * 128 + ((((lane >> 4) * 2)     ^ (arow & 7)) * 16);
    const int aoff1 = arow * 128 + ((((lane >> 4) * 2 + 1) ^ (arow & 7)) * 16);
    const int bbase = (wc + (lane & 15)) * 80 + (lane >> 4) * 16;  // + n*1280

    f32x4 acc[8];
#pragma unroll
    for (int n = 0; n < 8; ++n) acc[n] = f32x4{0.f, 0.f, 0.f, 0.f};

    // prologue: A(0) gload + B(0) register loads
    __builtin_amdgcn_global_load_lds((gvoid*)aSrc,
        (lvoid*)&As[0][w * 256], 16, 0, 0);
    f32x4 bv0 = *(const f32x4*)(bSrc);
    f32x4 bv1 = *(const f32x4*)(bSrc + 4);

#pragma unroll
    for (int T = 0; T < NS; ++T) {
        const int buf = T & 1;

        // cvt + publish B(T) into Bs[buf]
        u32x4 bw;
        bw[0] = cvt_pk_bf16(bv0.x, bv0.y);
        bw[1] = cvt_pk_bf16(bv0.z, bv0.w);
        bw[2] = cvt_pk_bf16(bv1.x, bv1.y);
        bw[3] = cvt_pk_bf16(bv1.z, bv1.w);
        *(u32x4*)(buf ? bDst1 : bDst0) = bw;

        // drain A(T) gload + my ds_write, then publish to the block
        asm volatile("s_waitcnt vmcnt(0) lgkmcnt(0)" ::: "memory");
        __builtin_amdgcn_s_barrier();

        // issue next tile's loads; they land during compute + barriers
        if (T + 1 < NS) {
            __builtin_amdgcn_global_load_lds((gvoid*)(aSrc + (T + 1) * BK),
                (lvoid*)&As[buf ^ 1][w * 256], 16, 0, 0);
            bv0 = *(const f32x4*)(bSrc + (T + 1) * BK);
            bv1 = *(const f32x4*)(bSrc + (T + 1) * BK + 4);
        }

        // A fragment: swizzled fp32 read + cvt to bf16
        const char* ab = (const char*)&As[buf][0];
        f32x4 alo = *(const f32x4*)(ab + aoff0);
        f32x4 ahi = *(const f32x4*)(ab + aoff1);
        union { u32 u[4]; s16x8 s; } afu;
        afu.u[0] = cvt_pk_bf16(alo.x, alo.y);
        afu.u[1] = cvt_pk_bf16(alo.z, alo.w);
        afu.u[2] = cvt_pk_bf16(ahi.x, ahi.y);
        afu.u[3] = cvt_pk_bf16(ahi.z, ahi.w);
        const s16x8 af = afu.s;

        const char* bb = (const char*)&Bs[buf][0];
#pragma unroll
        for (int n = 0; n < 8; ++n) {
            s16x8 bf = *(const s16x8*)(bb + bbase + n * 1280);
            acc[n] = __builtin_amdgcn_mfma_f32_16x16x32_bf16(af, bf, acc[n], 0, 0, 0);
        }

        // all my LDS reads retired, then free both buffers for next writes
        asm volatile("s_waitcnt lgkmcnt(0)" ::: "memory");
        __builtin_amdgcn_s_barrier();
    }

    // epilogue: C/D map col=lane&15, row=(lane>>4)*4+j (16x16 shape)
    float* outp = partials + (size_t)k * (NROW * NROW);
    const int crow0 = h * 128 + wr + (lane >> 4) * 4;
    const int ccol0 = wc + (lane & 15);
#pragma unroll
    for (int n = 0; n < 8; ++n) {
#pragma unroll
        for (int j = 0; j < 4; ++j) {
            __builtin_nontemporal_store(acc[n][j],
                outp + (size_t)(crow0 + j) * NROW + ccol0 + 16 * n);
        }
    }
}

// Stage 2: reduce partials over split; per-row masked exp, rowsum, pos, rowloss; store E.
__global__ __launch_bounds__(NROW) void reduce_loss_rows(
    const float* __restrict__ partials, const int* __restrict__ idx,
    float* __restrict__ E, float* __restrict__ rowloss, float* __restrict__ posbuf)
{
    const int b = blockIdx.x;   // row
    const int t = threadIdx.x;  // col
    const float* p = partials + b * NROW + t;
    float sum = 0.f;
#pragma unroll 8
    for (int s = 0; s < SPLIT; ++s)
        sum += p[(size_t)s * (NROW * NROW)];

    const float logit = sum * TEMP;
    const bool  mask  = (idx[b] != idx[t]) || (b == t);
    const float e     = mask ? expf(logit) : 0.0f;
    E[b * NROW + t] = e;

    __shared__ float red[NROW];
    __shared__ float posv;
    if (t == b) posv = logit;
    red[t] = e;
    __syncthreads();
#pragma unroll
    for (int s = NROW / 2; s > 0; s >>= 1) {
        if (t < s) red[t] += red[t + s];
        __syncthreads();
    }
    if (t == 0) {
        posbuf[b]  = posv;
        rowloss[b] = logf(red[0]) - posv;
    }
}

// Stage 3: column sums of E, column losses, final mean.
__global__ __launch_bounds__(NROW) void finalize_loss(
    const float* __restrict__ E, const float* __restrict__ rowloss,
    const float* __restrict__ posbuf, float* __restrict__ out)
{
    const int t = threadIdx.x;
    float csum = 0.f;
#pragma unroll 8
    for (int i = 0; i < NROW; ++i)
        csum += E[i * NROW + t];
    const float closs = logf(csum) - posbuf[t];
    const float rl    = rowloss[t];

    __shared__ float redc[NROW];
    __shared__ float redr[NROW];
    redc[t] = closs;
    redr[t] = rl;
    __syncthreads();
#pragma unroll
    for (int s = NROW / 2; s > 0; s >>= 1) {
        if (t < s) { redc[t] += redc[t + s]; redr[t] += redr[t + s]; }
        __syncthreads();
    }
    if (t == 0)
        out[0] = 0.5f * (redc[0] + redr[0]) * (1.0f / (float)NROW);
}

extern "C" void kernel_launch(void* const* d_in, const int* in_sizes, int n_in,
                              void* d_out, int out_size, void* d_ws, size_t ws_size,
                              hipStream_t stream)
{
    (void)in_sizes; (void)n_in; (void)out_size; (void)ws_size;
    const float* A   = (const float*)d_in[0];
    const float* Bm  = (const float*)d_in[1];
    const int*   idx = (const int*)d_in[2];
    float*       out = (float*)d_out;

    float* partials = (float*)d_ws;                       // 64 MB (split=256)
    float* E        = partials + (size_t)SPLIT * NROW * NROW;
    float* rowloss  = E + NROW * NROW;
    float* posbuf   = rowloss + NROW;

    gemm_pair<<<SPLIT * 2, TPB, 0, stream>>>(A, Bm, partials);
    reduce_loss_rows<<<NROW, NROW, 0, stream>>>(partials, idx, E, rowloss, posbuf);
    finalize_loss<<<1, NROW, 0, stream>>>(E, rowloss, posbuf, out);
}